// Round 5
// baseline (161.754 us; speedup 1.0000x reference)
//
#include <hip/hip_runtime.h>

#define DD 256
#define HH 4
#define NW 4   // waves per block; one GRAPH per wave (waves fully independent)

#define WAVE_LDS_FENCE() asm volatile("s_waitcnt lgkmcnt(0)" ::: "memory")
#define WAVE_VM_FENCE()  asm volatile("s_waitcnt vmcnt(0)" ::: "memory")
#define SCHED_FENCE()    asm volatile("" ::: "memory")   // source-level issue barrier

// starts[g] = lower_bound(bi, g); starts[G] = N   (bi is sorted)
__global__ void starts_kernel(const int* __restrict__ bi, int* __restrict__ starts,
                              int N, int G) {
    int g = blockIdx.x * blockDim.x + threadIdx.x;
    if (g > G) return;
    int lo = 0, hi = N;
    while (lo < hi) { int mid = (lo + hi) >> 1; if (bi[mid] < g) lo = mid + 1; else hi = mid; }
    starts[g] = lo;
}

// One wave per graph.
// Score phase: lane = row; loads issued in explicit 8-deep batches (one vmcnt wait
//              per 8 loads) to break the per-iteration latency serialization.
// Pooling phase: lane = column block, same 8-deep batching; weights via eb broadcast.
__global__ __launch_bounds__(256) void fused_batch(
    const float* __restrict__ x, const int* __restrict__ starts,
    const float* __restrict__ W, const float* __restrict__ b,
    const float* __restrict__ temp, float* __restrict__ scores_ws,
    float* __restrict__ xp, float* __restrict__ aw, int N, int G) {

    __shared__ float4 eb[NW][64];    // per-wave row-weight broadcast buffer (4 KB)

    const int t    = threadIdx.x;
    const int lane = t & 63;
    const int wid  = t >> 6;
    const int g = blockIdx.x * NW + wid;
    if (g >= G) return;

    const int s = starts[g];
    const int e = starts[g + 1];
    const int cnt = e - s;

    if (cnt == 0) {
        ((float4*)xp)[(size_t)g * 64 + lane] = make_float4(0.f, 0.f, 0.f, 0.f);
        return;
    }

    const float4* __restrict__ x4 = (const float4*)x;
    const float4* __restrict__ W4 = (const float4*)W;   // wave-uniform indexed
    const float invT = 1.0f / temp[0];
    const float b0 = b[0], b1 = b[1], b2 = b[2], b3 = b[3];

    const int ngrp = (cnt + 63) >> 6;   // almost always 1 (mean cnt ~31)

    float m0 = -1e30f, m1 = -1e30f, m2 = -1e30f, m3 = -1e30f;
    float q0 = 0.f, q1 = 0.f, q2 = 0.f, q3 = 0.f;   // fast path: my row's scores
    bool v0 = false;

    if (ngrp == 1) {
        const int r  = s + lane;
        v0 = (r < e);
        const int rc = v0 ? r : (e - 1);
        const float4* __restrict__ xr = x4 + (size_t)rc * 64;
        float t0 = 0.f, t1 = 0.f, t2 = 0.f, t3 = 0.f;
        #pragma unroll
        for (int base = 0; base < 64; base += 8) {
            float4 xv[8];
            #pragma unroll
            for (int k = 0; k < 8; ++k) xv[k] = xr[base + k];   // 8 loads in flight
            SCHED_FENCE();                                      // keep the batch issued
            #pragma unroll
            for (int k = 0; k < 8; ++k) {
                const int d = base + k;
                const float4 w0 = W4[d],       w1 = W4[64 + d];
                const float4 w2 = W4[128 + d], w3 = W4[192 + d];
                t0 += xv[k].x*w0.x + xv[k].y*w0.y + xv[k].z*w0.z + xv[k].w*w0.w;
                t1 += xv[k].x*w1.x + xv[k].y*w1.y + xv[k].z*w1.z + xv[k].w*w1.w;
                t2 += xv[k].x*w2.x + xv[k].y*w2.y + xv[k].z*w2.z + xv[k].w*w2.w;
                t3 += xv[k].x*w3.x + xv[k].y*w3.y + xv[k].z*w3.z + xv[k].w*w3.w;
            }
        }
        q0 = (t0 + b0) * invT; q1 = (t1 + b1) * invT;
        q2 = (t2 + b2) * invT; q3 = (t3 + b3) * invT;
        if (v0) { m0 = q0; m1 = q1; m2 = q2; m3 = q3; }
    } else {
        // rare path: multiple 64-row groups; scores round-trip via workspace
        for (int grp = 0; grp < ngrp; ++grp) {
            const int r  = s + grp * 64 + lane;
            const bool v = (r < e);
            const int rc = v ? r : (e - 1);
            const float4* __restrict__ xr = x4 + (size_t)rc * 64;
            float t0 = 0.f, t1 = 0.f, t2 = 0.f, t3 = 0.f;
            #pragma unroll
            for (int base = 0; base < 64; base += 8) {
                float4 xv[8];
                #pragma unroll
                for (int k = 0; k < 8; ++k) xv[k] = xr[base + k];
                SCHED_FENCE();
                #pragma unroll
                for (int k = 0; k < 8; ++k) {
                    const int d = base + k;
                    const float4 w0 = W4[d],       w1 = W4[64 + d];
                    const float4 w2 = W4[128 + d], w3 = W4[192 + d];
                    t0 += xv[k].x*w0.x + xv[k].y*w0.y + xv[k].z*w0.z + xv[k].w*w0.w;
                    t1 += xv[k].x*w1.x + xv[k].y*w1.y + xv[k].z*w1.z + xv[k].w*w1.w;
                    t2 += xv[k].x*w2.x + xv[k].y*w2.y + xv[k].z*w2.z + xv[k].w*w2.w;
                    t3 += xv[k].x*w3.x + xv[k].y*w3.y + xv[k].z*w3.z + xv[k].w*w3.w;
                }
            }
            const float s0 = (t0 + b0) * invT, s1 = (t1 + b1) * invT;
            const float s2 = (t2 + b2) * invT, s3 = (t3 + b3) * invT;
            if (v) {
                ((float4*)scores_ws)[r] = make_float4(s0, s1, s2, s3);
                m0 = fmaxf(m0, s0); m1 = fmaxf(m1, s1);
                m2 = fmaxf(m2, s2); m3 = fmaxf(m3, s3);
            }
        }
    }

    // per-graph butterfly max (once per graph)
    #pragma unroll
    for (int off = 32; off; off >>= 1) {
        m0 = fmaxf(m0, __shfl_xor(m0, off));
        m1 = fmaxf(m1, __shfl_xor(m1, off));
        m2 = fmaxf(m2, __shfl_xor(m2, off));
        m3 = fmaxf(m3, __shfl_xor(m3, off));
    }

    float l0 = 0.f, l1 = 0.f, l2 = 0.f, l3 = 0.f;
    float4 ac0 = make_float4(0.f,0.f,0.f,0.f), ac1 = ac0, ac2 = ac0, ac3 = ac0;
    float e0 = 0.f, e1 = 0.f, e2 = 0.f, e3 = 0.f;   // fast-path unnormalized weights

    if (ngrp == 1) {
        if (v0) {
            e0 = __expf(q0 - m0); e1 = __expf(q1 - m1);
            e2 = __expf(q2 - m2); e3 = __expf(q3 - m3);
        }
        l0 = e0; l1 = e1; l2 = e2; l3 = e3;
        eb[wid][lane] = make_float4(e0, e1, e2, e3);
        WAVE_LDS_FENCE();
        // pooling: lane = column block; 8-deep batched re-read (L2-hot)
        for (int i0 = 0; i0 < cnt; i0 += 8) {
            const int nb = cnt - i0 < 8 ? cnt - i0 : 8;
            float4 xv[8];
            #pragma unroll
            for (int k = 0; k < 8; ++k)
                if (k < nb) xv[k] = x4[(size_t)(s + i0 + k) * 64 + lane];
            SCHED_FENCE();
            #pragma unroll
            for (int k = 0; k < 8; ++k) {
                if (k < nb) {
                    const float4 ee = eb[wid][i0 + k];   // lane-uniform broadcast
                    ac0.x += ee.x*xv[k].x; ac0.y += ee.x*xv[k].y; ac0.z += ee.x*xv[k].z; ac0.w += ee.x*xv[k].w;
                    ac1.x += ee.y*xv[k].x; ac1.y += ee.y*xv[k].y; ac1.z += ee.y*xv[k].z; ac1.w += ee.y*xv[k].w;
                    ac2.x += ee.z*xv[k].x; ac2.y += ee.z*xv[k].y; ac2.z += ee.z*xv[k].z; ac2.w += ee.z*xv[k].w;
                    ac3.x += ee.w*xv[k].x; ac3.y += ee.w*xv[k].y; ac3.z += ee.w*xv[k].z; ac3.w += ee.w*xv[k].w;
                }
            }
        }
    } else {
        WAVE_VM_FENCE();   // our scores_ws stores visible before same-wave readback
        for (int grp = 0; grp < ngrp; ++grp) {
            const int base = s + grp * 64;
            const int r = base + lane;
            const bool v = (r < e);
            const int rc = v ? r : (e - 1);
            const float4 sv = ((const float4*)scores_ws)[rc];
            float f0 = 0.f, f1 = 0.f, f2 = 0.f, f3 = 0.f;
            if (v) {
                f0 = __expf(sv.x - m0); f1 = __expf(sv.y - m1);
                f2 = __expf(sv.z - m2); f3 = __expf(sv.w - m3);
            }
            l0 += f0; l1 += f1; l2 += f2; l3 += f3;
            WAVE_LDS_FENCE();                 // previous group's reads complete
            eb[wid][lane] = make_float4(f0, f1, f2, f3);
            WAVE_LDS_FENCE();
            const int cs = min(64, e - base);
            for (int i0 = 0; i0 < cs; i0 += 8) {
                const int nb = cs - i0 < 8 ? cs - i0 : 8;
                float4 xv[8];
                #pragma unroll
                for (int k = 0; k < 8; ++k)
                    if (k < nb) xv[k] = x4[(size_t)(base + i0 + k) * 64 + lane];
                SCHED_FENCE();
                #pragma unroll
                for (int k = 0; k < 8; ++k) {
                    if (k < nb) {
                        const float4 ee = eb[wid][i0 + k];
                        ac0.x += ee.x*xv[k].x; ac0.y += ee.x*xv[k].y; ac0.z += ee.x*xv[k].z; ac0.w += ee.x*xv[k].w;
                        ac1.x += ee.y*xv[k].x; ac1.y += ee.y*xv[k].y; ac1.z += ee.y*xv[k].z; ac1.w += ee.y*xv[k].w;
                        ac2.x += ee.z*xv[k].x; ac2.y += ee.z*xv[k].y; ac2.z += ee.z*xv[k].z; ac2.w += ee.z*xv[k].w;
                        ac3.x += ee.w*xv[k].x; ac3.y += ee.w*xv[k].y; ac3.z += ee.w*xv[k].z; ac3.w += ee.w*xv[k].w;
                    }
                }
            }
        }
    }

    // per-graph butterfly sum
    #pragma unroll
    for (int off = 32; off; off >>= 1) {
        l0 += __shfl_xor(l0, off);
        l1 += __shfl_xor(l1, off);
        l2 += __shfl_xor(l2, off);
        l3 += __shfl_xor(l3, off);
    }

    const float il0 = 1.f/l0, il1 = 1.f/l1, il2 = 1.f/l2, il3 = 1.f/l3;
    float4 out;
    out.x = 0.25f*(ac0.x*il0 + ac1.x*il1 + ac2.x*il2 + ac3.x*il3);
    out.y = 0.25f*(ac0.y*il0 + ac1.y*il1 + ac2.y*il2 + ac3.y*il3);
    out.z = 0.25f*(ac0.z*il0 + ac1.z*il1 + ac2.z*il2 + ac3.z*il3);
    out.w = 0.25f*(ac0.w*il0 + ac1.w*il1 + ac2.w*il2 + ac3.w*il3);
    ((float4*)xp)[(size_t)g * 64 + lane] = out;

    // attention weights [H, N]: lane = row, coalesced within graph range
    if (ngrp == 1) {
        if (v0) {
            const int r = s + lane;
            aw[0 * (size_t)N + r] = e0 * il0;
            aw[1 * (size_t)N + r] = e1 * il1;
            aw[2 * (size_t)N + r] = e2 * il2;
            aw[3 * (size_t)N + r] = e3 * il3;
        }
    } else {
        for (int grp = 0; grp < ngrp; ++grp) {
            const int r = s + grp * 64 + lane;
            if (r < e) {
                const float4 sv = ((const float4*)scores_ws)[r];
                aw[0 * (size_t)N + r] = __expf(sv.x - m0) * il0;
                aw[1 * (size_t)N + r] = __expf(sv.y - m1) * il1;
                aw[2 * (size_t)N + r] = __expf(sv.z - m2) * il2;
                aw[3 * (size_t)N + r] = __expf(sv.w - m3) * il3;
            }
        }
    }
}

extern "C" void kernel_launch(void* const* d_in, const int* in_sizes, int n_in,
                              void* d_out, int out_size, void* d_ws, size_t ws_size,
                              hipStream_t stream) {
    const float* x    = (const float*)d_in[0];
    const int*   bi   = (const int*)d_in[1];
    // d_in[2] = num_graphs (derived from out_size)
    const float* W    = (const float*)d_in[3];
    const float* b    = (const float*)d_in[4];
    const float* temp = (const float*)d_in[5];

    const int N = in_sizes[0] / DD;
    const int G = (out_size - HH * N) / DD;

    float* xp = (float*)d_out;                    // [G, D]
    float* aw = (float*)d_out + (size_t)G * DD;   // [H, N]

    float* scores_ws = (float*)d_ws;                               // N*H floats
    int*   starts    = (int*)((char*)d_ws + (size_t)N * HH * 4);   // G+1 ints

    starts_kernel<<<(G + 1 + 255) / 256, 256, 0, stream>>>(bi, starts, N, G);
    fused_batch<<<(G + NW - 1) / NW, 256, 0, stream>>>(
        x, starts, W, b, temp, scores_ws, xp, aw, N, G);
}

// Round 6
// 133.794 us; speedup vs baseline: 1.2090x; 1.2090x over previous
//
#include <hip/hip_runtime.h>

#define DD 256
#define HH 4

#define WAVE_VM_FENCE()  asm volatile("s_waitcnt vmcnt(0)" ::: "memory")

// starts[g] = lower_bound(bi, g); starts[G] = N   (bi is sorted)
__global__ void starts_kernel(const int* __restrict__ bi, int* __restrict__ starts,
                              int N, int G) {
    int g = blockIdx.x * blockDim.x + threadIdx.x;
    if (g > G) return;
    int lo = 0, hi = N;
    while (lo < hi) { int mid = (lo + hi) >> 1; if (bi[mid] < g) lo = mid + 1; else hi = mid; }
    starts[g] = lo;
}

// ONE BLOCK (4 waves) per GRAPH.
// Score phase: lane = row, waves split the 64-column loop 4 ways (chain 64 -> 16),
//              partial dots merged through LDS.
// Pool phase:  lane = column, waves split rows 4 ways (chain ~31 -> ~8),
//              accumulators merged through LDS. aw: wave w writes head w.
__global__ __launch_bounds__(256) void fused_qw(
    const float* __restrict__ x, const int* __restrict__ starts,
    const float* __restrict__ W, const float* __restrict__ b,
    const float* __restrict__ temp, float* __restrict__ scores_ws,
    float* __restrict__ xp, float* __restrict__ aw, int N, int G) {

    __shared__ float4 part[4][64];      // per-wave partial dots      (4 KB)
    __shared__ float4 ebuf[64];         // per-row unnormalized wts   (1 KB)
    __shared__ float4 accm[3][4][64];   // waves 1..3 pooled partials (12 KB)

    const int t    = threadIdx.x;
    const int lane = t & 63;
    const int wid  = t >> 6;
    const int g    = blockIdx.x;

    const int s = starts[g];
    const int e = starts[g + 1];
    const int cnt = e - s;
    const int ngrp = cnt > 0 ? ((cnt + 63) >> 6) : 1;   // block-uniform

    const float4* __restrict__ x4 = (const float4*)x;
    const float4* __restrict__ W4 = (const float4*)W;   // wave-uniform indexed
    const float invT = 1.0f / temp[0];
    const float b0 = b[0], b1 = b[1], b2 = b[2], b3 = b[3];

    float m0 = -1e30f, m1 = -1e30f, m2 = -1e30f, m3 = -1e30f;
    float q0 = 0.f, q1 = 0.f, q2 = 0.f, q3 = 0.f;   // merged scores (authoritative if ngrp==1)
    bool v0 = false;

    // ---------- Phase A: scores (column-split 4 ways) ----------
    for (int grp = 0; grp < ngrp; ++grp) {
        const int r = s + grp * 64 + lane;
        const bool v = (cnt > 0) && (r < e);
        float t0 = 0.f, t1 = 0.f, t2 = 0.f, t3 = 0.f;
        if (cnt > 0) {
            const int rc = v ? r : (e - 1);
            const float4* __restrict__ xr = x4 + (size_t)rc * 64 + wid * 16;
            const float4* __restrict__ wr = W4 + wid * 16;
            #pragma unroll 8
            for (int d = 0; d < 16; ++d) {
                const float4 xv = xr[d];
                const float4 w0 = wr[d],       w1 = wr[64 + d];
                const float4 w2 = wr[128 + d], w3 = wr[192 + d];
                t0 += xv.x*w0.x + xv.y*w0.y + xv.z*w0.z + xv.w*w0.w;
                t1 += xv.x*w1.x + xv.y*w1.y + xv.z*w1.z + xv.w*w1.w;
                t2 += xv.x*w2.x + xv.y*w2.y + xv.z*w2.z + xv.w*w2.w;
                t3 += xv.x*w3.x + xv.y*w3.y + xv.z*w3.z + xv.w*w3.w;
            }
        }
        part[wid][lane] = make_float4(t0, t1, t2, t3);
        __syncthreads();
        const float4 pA = part[(wid + 1) & 3][lane];
        const float4 pB = part[(wid + 2) & 3][lane];
        const float4 pC = part[(wid + 3) & 3][lane];
        __syncthreads();                      // part reusable next grp
        q0 = (t0 + pA.x + pB.x + pC.x + b0) * invT;
        q1 = (t1 + pA.y + pB.y + pC.y + b1) * invT;
        q2 = (t2 + pA.z + pB.z + pC.z + b2) * invT;
        q3 = (t3 + pA.w + pB.w + pC.w + b3) * invT;
        if (v) {
            m0 = fmaxf(m0, q0); m1 = fmaxf(m1, q1);
            m2 = fmaxf(m2, q2); m3 = fmaxf(m3, q3);
            if (ngrp > 1)       // every wave stores (same value) -> own-wave readback later
                ((float4*)scores_ws)[r] = make_float4(q0, q1, q2, q3);
        }
        v0 = v;
    }

    // per-graph butterfly max (each wave computes identical result)
    #pragma unroll
    for (int off = 32; off; off >>= 1) {
        m0 = fmaxf(m0, __shfl_xor(m0, off));
        m1 = fmaxf(m1, __shfl_xor(m1, off));
        m2 = fmaxf(m2, __shfl_xor(m2, off));
        m3 = fmaxf(m3, __shfl_xor(m3, off));
    }

    // ---------- Phase B: exp + denom + pooling (row-split 4 ways) ----------
    float l0 = 0.f, l1 = 0.f, l2 = 0.f, l3 = 0.f;
    float4 ac0 = make_float4(0.f,0.f,0.f,0.f), ac1 = ac0, ac2 = ac0, ac3 = ac0;
    float fe0 = 0.f, fe1 = 0.f, fe2 = 0.f, fe3 = 0.f;  // fast-path weights (lane's row)

    if (ngrp > 1) WAVE_VM_FENCE();           // our scores_ws stores before readback

    for (int grp = 0; grp < ngrp; ++grp) {
        const int base = s + grp * 64;
        const int r = base + lane;
        const bool v = (cnt > 0) && (r < e);
        float e0 = 0.f, e1 = 0.f, e2 = 0.f, e3 = 0.f;
        if (v) {
            float s0, s1, s2, s3;
            if (ngrp == 1) { s0 = q0; s1 = q1; s2 = q2; s3 = q3; }
            else { const float4 sv = ((const float4*)scores_ws)[r];
                   s0 = sv.x; s1 = sv.y; s2 = sv.z; s3 = sv.w; }
            e0 = __expf(s0 - m0); e1 = __expf(s1 - m1);
            e2 = __expf(s2 - m2); e3 = __expf(s3 - m3);
        }
        l0 += e0; l1 += e1; l2 += e2; l3 += e3;
        if (ngrp == 1) { fe0 = e0; fe1 = e1; fe2 = e2; fe3 = e3; }
        if (wid == 0) ebuf[lane] = make_float4(e0, e1, e2, e3);
        __syncthreads();
        const int cs = (cnt > 0) ? min(64, e - base) : 0;
        const int qs = (cs + 3) >> 2;
        const int i1 = min(cs, (wid + 1) * qs);
        for (int i = wid * qs; i < i1; ++i) {
            const float4 xv = x4[(size_t)(base + i) * 64 + lane];
            const float4 ee = ebuf[i];       // lane-uniform broadcast
            ac0.x += ee.x*xv.x; ac0.y += ee.x*xv.y; ac0.z += ee.x*xv.z; ac0.w += ee.x*xv.w;
            ac1.x += ee.y*xv.x; ac1.y += ee.y*xv.y; ac1.z += ee.y*xv.z; ac1.w += ee.y*xv.w;
            ac2.x += ee.z*xv.x; ac2.y += ee.z*xv.y; ac2.z += ee.z*xv.z; ac2.w += ee.z*xv.w;
            ac3.x += ee.w*xv.x; ac3.y += ee.w*xv.y; ac3.z += ee.w*xv.z; ac3.w += ee.w*xv.w;
        }
        __syncthreads();                     // ebuf reusable next grp
    }

    // per-graph butterfly sum (identical in every wave)
    #pragma unroll
    for (int off = 32; off; off >>= 1) {
        l0 += __shfl_xor(l0, off);
        l1 += __shfl_xor(l1, off);
        l2 += __shfl_xor(l2, off);
        l3 += __shfl_xor(l3, off);
    }
    const float il0 = 1.f/l0, il1 = 1.f/l1, il2 = 1.f/l2, il3 = 1.f/l3;

    // ---------- accumulator merge + pooled output ----------
    if (wid != 0) {
        accm[wid - 1][0][lane] = ac0; accm[wid - 1][1][lane] = ac1;
        accm[wid - 1][2][lane] = ac2; accm[wid - 1][3][lane] = ac3;
    }
    __syncthreads();
    if (wid == 0) {
        float4 out = make_float4(0.f, 0.f, 0.f, 0.f);
        if (cnt > 0) {
            #pragma unroll
            for (int w = 0; w < 3; ++w) {
                const float4 r0 = accm[w][0][lane], r1 = accm[w][1][lane];
                const float4 r2 = accm[w][2][lane], r3 = accm[w][3][lane];
                ac0.x += r0.x; ac0.y += r0.y; ac0.z += r0.z; ac0.w += r0.w;
                ac1.x += r1.x; ac1.y += r1.y; ac1.z += r1.z; ac1.w += r1.w;
                ac2.x += r2.x; ac2.y += r2.y; ac2.z += r2.z; ac2.w += r2.w;
                ac3.x += r3.x; ac3.y += r3.y; ac3.z += r3.z; ac3.w += r3.w;
            }
            out.x = 0.25f*(ac0.x*il0 + ac1.x*il1 + ac2.x*il2 + ac3.x*il3);
            out.y = 0.25f*(ac0.y*il0 + ac1.y*il1 + ac2.y*il2 + ac3.y*il3);
            out.z = 0.25f*(ac0.z*il0 + ac1.z*il1 + ac2.z*il2 + ac3.z*il3);
            out.w = 0.25f*(ac0.w*il0 + ac1.w*il1 + ac2.w*il2 + ac3.w*il3);
        }
        ((float4*)xp)[(size_t)g * 64 + lane] = out;
    }

    // ---------- attention weights: wave w writes head w ----------
    if (cnt > 0) {
        const float mh  = (wid == 0) ? m0  : (wid == 1) ? m1  : (wid == 2) ? m2  : m3;
        const float ilh = (wid == 0) ? il0 : (wid == 1) ? il1 : (wid == 2) ? il2 : il3;
        if (ngrp == 1) {
            if (v0) {
                const float eh = (wid == 0) ? fe0 : (wid == 1) ? fe1 : (wid == 2) ? fe2 : fe3;
                aw[(size_t)wid * N + s + lane] = eh * ilh;
            }
        } else {
            for (int grp = 0; grp < ngrp; ++grp) {
                const int r = s + grp * 64 + lane;
                if (r < e) {
                    const float4 sv = ((const float4*)scores_ws)[r];
                    const float qh = (wid == 0) ? sv.x : (wid == 1) ? sv.y
                                   : (wid == 2) ? sv.z : sv.w;
                    aw[(size_t)wid * N + r] = __expf(qh - mh) * ilh;
                }
            }
        }
    }
}

extern "C" void kernel_launch(void* const* d_in, const int* in_sizes, int n_in,
                              void* d_out, int out_size, void* d_ws, size_t ws_size,
                              hipStream_t stream) {
    const float* x    = (const float*)d_in[0];
    const int*   bi   = (const int*)d_in[1];
    // d_in[2] = num_graphs (derived from out_size)
    const float* W    = (const float*)d_in[3];
    const float* b    = (const float*)d_in[4];
    const float* temp = (const float*)d_in[5];

    const int N = in_sizes[0] / DD;
    const int G = (out_size - HH * N) / DD;

    float* xp = (float*)d_out;                    // [G, D]
    float* aw = (float*)d_out + (size_t)G * DD;   // [H, N]

    float* scores_ws = (float*)d_ws;                               // N*H floats
    int*   starts    = (int*)((char*)d_ws + (size_t)N * HH * 4);   // G+1 ints

    starts_kernel<<<(G + 1 + 255) / 256, 256, 0, stream>>>(bi, starts, N, G);
    fused_qw<<<G, 256, 0, stream>>>(
        x, starts, W, b, temp, scores_ws, xp, aw, N, G);
}

// Round 7
// 101.337 us; speedup vs baseline: 1.5962x; 1.3203x over previous
//
#include <hip/hip_runtime.h>

#define DD 256
#define HH 4
#define NW 4   // waves per block in pool kernel; one GRAPH per wave

#define WAVE_LDS_FENCE() asm volatile("s_waitcnt lgkmcnt(0)" ::: "memory")

// starts[g] = lower_bound(bi, g); starts[G] = N   (bi is sorted)
__global__ void starts_kernel(const int* __restrict__ bi, int* __restrict__ starts,
                              int N, int G) {
    int g = blockIdx.x * blockDim.x + threadIdx.x;
    if (g > G) return;
    int lo = 0, hi = N;
    while (lo < hi) { int mid = (lo + hi) >> 1; if (bi[mid] < g) lo = mid + 1; else hi = mid; }
    starts[g] = lo;
}

// Kernel A: per-row unnormalized weights e[r][h] = exp((x[r]·W[h] + b[h]) / T).
// Quad layout: 4 lanes per row, 16 rows per wave-pass. Every global access is a
// fully-consumed 64B line; store is 256B linear. No softmax state, no graph logic.
__global__ __launch_bounds__(256) void score_kernel(
    const float* __restrict__ x, const float* __restrict__ W,
    const float* __restrict__ b, const float* __restrict__ temp,
    float* __restrict__ ew, int N) {

    const int lane = threadIdx.x & 63;
    const int rg   = lane >> 2;       // row within 16-row group
    const int cg   = lane & 3;        // quarter of the row
    const long wave  = (blockIdx.x * (long)blockDim.x + threadIdx.x) >> 6;
    const long nwav  = ((long)gridDim.x * blockDim.x) >> 6;

    const float4* __restrict__ x4 = (const float4*)x;
    const float4* __restrict__ W4 = (const float4*)W;
    const float invT = 1.0f / temp[0];
    const float bh   = b[cg];

    for (long r0 = wave * 16; r0 < N; r0 += nwav * 16) {
        const int row = (int)r0 + rg;
        const int rc  = row < N ? row : N - 1;
        const float4* __restrict__ xr = x4 + (size_t)rc * 64 + cg;
        float t0 = 0.f, t1 = 0.f, t2 = 0.f, t3 = 0.f;
        #pragma unroll 8
        for (int k = 0; k < 16; ++k) {
            const float4 xv = xr[4 * k];                 // quad covers one 64B line
            const float4 w0 = W4[      cg + 4 * k];
            const float4 w1 = W4[ 64 + cg + 4 * k];
            const float4 w2 = W4[128 + cg + 4 * k];
            const float4 w3 = W4[192 + cg + 4 * k];
            t0 += xv.x*w0.x + xv.y*w0.y + xv.z*w0.z + xv.w*w0.w;
            t1 += xv.x*w1.x + xv.y*w1.y + xv.z*w1.z + xv.w*w1.w;
            t2 += xv.x*w2.x + xv.y*w2.y + xv.z*w2.z + xv.w*w2.w;
            t3 += xv.x*w3.x + xv.y*w3.y + xv.z*w3.z + xv.w*w3.w;
        }
        // quad reduce: every quad lane ends with all four full dots
        t0 += __shfl_xor(t0, 1); t0 += __shfl_xor(t0, 2);
        t1 += __shfl_xor(t1, 1); t1 += __shfl_xor(t1, 2);
        t2 += __shfl_xor(t2, 1); t2 += __shfl_xor(t2, 2);
        t3 += __shfl_xor(t3, 1); t3 += __shfl_xor(t3, 2);
        const float th = (cg == 0) ? t0 : (cg == 1) ? t1 : (cg == 2) ? t2 : t3;
        if (row < N)
            ew[r0 * 4 + lane] = __expf((th + bh) * invT);   // 256B linear store
    }
}

// Kernel B: per-graph pooling + attention weights from precomputed e.
// One wave per graph; lane = column block (all x reads coalesced 1KB/instr).
// l (denominator) is lane-uniform -> no cross-lane reduction at all.
__global__ __launch_bounds__(256) void pool_kernel(
    const float* __restrict__ x, const int* __restrict__ starts,
    const float* __restrict__ ew, float* __restrict__ xp,
    float* __restrict__ aw, int N, int G) {

    __shared__ float4 eb[NW][64];    // per-wave row-weight broadcast (4 KB)

    const int t    = threadIdx.x;
    const int lane = t & 63;
    const int wid  = t >> 6;
    const int g = blockIdx.x * NW + wid;
    if (g >= G) return;

    const int s = starts[g];
    const int e = starts[g + 1];
    const int cnt = e - s;

    if (cnt == 0) {
        ((float4*)xp)[(size_t)g * 64 + lane] = make_float4(0.f, 0.f, 0.f, 0.f);
        return;
    }

    const float4* __restrict__ x4 = (const float4*)x;
    const float4* __restrict__ e4 = (const float4*)ew;
    const int ngrp = (cnt + 63) >> 6;   // almost always 1 (mean cnt ~31)

    float l0 = 0.f, l1 = 0.f, l2 = 0.f, l3 = 0.f;
    float4 ac0 = make_float4(0.f,0.f,0.f,0.f), ac1 = ac0, ac2 = ac0, ac3 = ac0;

    for (int grp = 0; grp < ngrp; ++grp) {
        const int base = s + grp * 64;
        const int r = base + lane;
        WAVE_LDS_FENCE();                       // prior grp's eb reads retired
        if (r < e) eb[wid][lane] = e4[r];       // coalesced e stage
        WAVE_LDS_FENCE();
        const int cs = min(64, e - base);
        for (int i = 0; i < cs; ++i) {
            const float4 xv = x4[(size_t)(base + i) * 64 + lane];   // coalesced
            const float4 ee = eb[wid][i];       // lane-uniform broadcast
            l0 += ee.x; l1 += ee.y; l2 += ee.z; l3 += ee.w;
            ac0.x += ee.x*xv.x; ac0.y += ee.x*xv.y; ac0.z += ee.x*xv.z; ac0.w += ee.x*xv.w;
            ac1.x += ee.y*xv.x; ac1.y += ee.y*xv.y; ac1.z += ee.y*xv.z; ac1.w += ee.y*xv.w;
            ac2.x += ee.z*xv.x; ac2.y += ee.z*xv.y; ac2.z += ee.z*xv.z; ac2.w += ee.z*xv.w;
            ac3.x += ee.w*xv.x; ac3.y += ee.w*xv.y; ac3.z += ee.w*xv.z; ac3.w += ee.w*xv.w;
        }
    }
    // NOTE: l accumulated once per lane over all rows -> 64x redundant but uniform;
    // every lane holds the full denominator. No butterfly needed.

    const float il0 = 1.f/l0, il1 = 1.f/l1, il2 = 1.f/l2, il3 = 1.f/l3;
    float4 out;
    out.x = 0.25f*(ac0.x*il0 + ac1.x*il1 + ac2.x*il2 + ac3.x*il3);
    out.y = 0.25f*(ac0.y*il0 + ac1.y*il1 + ac2.y*il2 + ac3.y*il3);
    out.z = 0.25f*(ac0.z*il0 + ac1.z*il1 + ac2.z*il2 + ac3.z*il3);
    out.w = 0.25f*(ac0.w*il0 + ac1.w*il1 + ac2.w*il2 + ac3.w*il3);
    ((float4*)xp)[(size_t)g * 64 + lane] = out;

    // attention weights [H, N]
    if (ngrp == 1) {
        if (lane < cnt) {
            const float4 ev = eb[wid][lane];
            aw[0 * (size_t)N + s + lane] = ev.x * il0;
            aw[1 * (size_t)N + s + lane] = ev.y * il1;
            aw[2 * (size_t)N + s + lane] = ev.z * il2;
            aw[3 * (size_t)N + s + lane] = ev.w * il3;
        }
    } else {
        for (int grp = 0; grp < ngrp; ++grp) {
            const int r = s + grp * 64 + lane;
            if (r < e) {
                const float4 ev = e4[r];
                aw[0 * (size_t)N + r] = ev.x * il0;
                aw[1 * (size_t)N + r] = ev.y * il1;
                aw[2 * (size_t)N + r] = ev.z * il2;
                aw[3 * (size_t)N + r] = ev.w * il3;
            }
        }
    }
}

extern "C" void kernel_launch(void* const* d_in, const int* in_sizes, int n_in,
                              void* d_out, int out_size, void* d_ws, size_t ws_size,
                              hipStream_t stream) {
    const float* x    = (const float*)d_in[0];
    const int*   bi   = (const int*)d_in[1];
    // d_in[2] = num_graphs (derived from out_size)
    const float* W    = (const float*)d_in[3];
    const float* b    = (const float*)d_in[4];
    const float* temp = (const float*)d_in[5];

    const int N = in_sizes[0] / DD;
    const int G = (out_size - HH * N) / DD;

    float* xp = (float*)d_out;                    // [G, D]
    float* aw = (float*)d_out + (size_t)G * DD;   // [H, N]

    float* ew     = (float*)d_ws;                                  // N*H floats
    int*   starts = (int*)((char*)d_ws + (size_t)N * HH * 4);      // G+1 ints

    starts_kernel<<<(G + 1 + 255) / 256, 256, 0, stream>>>(bi, starts, N, G);
    score_kernel<<<2048, 256, 0, stream>>>(x, W, b, temp, ew, N);
    pool_kernel<<<(G + NW - 1) / NW, 256, 0, stream>>>(x, starts, ew, xp, aw, N, G);
}